// Round 14
// baseline (340.847 us; speedup 1.0000x reference)
//
#include <hip/hip_runtime.h>

typedef unsigned short u16;
typedef unsigned int u32;
typedef __attribute__((ext_vector_type(8))) short short8;
typedef __attribute__((ext_vector_type(4))) short s16x4;
typedef __attribute__((ext_vector_type(4))) float f32x4;
typedef __attribute__((ext_vector_type(2))) float f32x2;
typedef __attribute__((ext_vector_type(2))) int i32x2;

#define BB 512
#define TT 128
#define DD 128
#define HH 4
#define NBB 2
#define BT (BB*TT)
#define EPSF 1e-5f
#define LOG2E 1.4426950408889634f

__device__ __forceinline__ float bf2f(u16 u){ return __uint_as_float(((u32)u) << 16); }
__device__ __forceinline__ u16 f2bf(float f){
  u32 x = __float_as_uint(f);
  u32 r = x + 0x7fffu + ((x >> 16) & 1u);
  return (u16)(r >> 16);
}
__device__ __forceinline__ float bcastf(float v, int lane){
  return __uint_as_float(__builtin_amdgcn_readlane(__float_as_uint(v), lane));
}
// gelu (tanh approx) with rcp/exp2 only
__device__ __forceinline__ float gelu_fast(float x){
  float u = 0.7978845608028654f * (x + 0.044715f * x * x * x);
  float e2 = __builtin_amdgcn_exp2f(2.f * LOG2E * u);
  return x - x * __builtin_amdgcn_rcpf(e2 + 1.f);
}
#define DPP_ADD(v, ctrl, rmask, bc) \
  v += __int_as_float(__builtin_amdgcn_update_dpp(0, __float_as_int(v), (ctrl), (rmask), 0xf, (bc)))
// full-wave (64-lane) sum via DPP, broadcast to all lanes through SGPR
__device__ __forceinline__ float wsum64(float v){
  DPP_ADD(v, 0x111, 0xf, true);
  DPP_ADD(v, 0x112, 0xf, true);
  DPP_ADD(v, 0x114, 0xf, true);
  DPP_ADD(v, 0x118, 0xf, true);
  DPP_ADD(v, 0x142, 0xa, false);
  DPP_ADD(v, 0x143, 0xc, false);
  return bcastf(v, 63);
}
// sum over lanes 0..31; total lands in lane 31
__device__ __forceinline__ float rsum_rows01(float v){
  DPP_ADD(v, 0x111, 0xf, true);
  DPP_ADD(v, 0x112, 0xf, true);
  DPP_ADD(v, 0x114, 0xf, true);
  DPP_ADD(v, 0x118, 0xf, true);
  DPP_ADD(v, 0x142, 0xa, false);
  return v;
}
// lanes<32 receive v from lane+32 (VALU permlane32_swap; no LDS).
__device__ __forceinline__ float down32(float v){
  i32x2 r = __builtin_amdgcn_permlane32_swap(__float_as_int(v), __float_as_int(v), false, false);
  return __int_as_float(r.y);
}

// ---------------- weight conversion to bf16 (transposed for MFMA B-frags) ----
__global__ __launch_bounds__(256) void k_convert(
    const float* __restrict__ ff_w1, const float* __restrict__ ff_w2,
    const float* __restrict__ Wi, const float* __restrict__ Wf,
    const float* __restrict__ Wz, const float* __restrict__ Wo,
    u16* __restrict__ w1T, u16* __restrict__ w2T,
    u16* __restrict__ gifT, u16* __restrict__ gzoT){
  int tid = blockIdx.x * 256 + threadIdx.x;
  const int n1 = NBB*384*128;
  if (tid < n1){
    int nb = tid / (384*128); int r = tid - nb*384*128; int n = r >> 7, k = r & 127;
    w1T[tid] = f2bf(ff_w1[(nb*128 + k)*384 + n]); return;
  }
  tid -= n1;
  const int n2 = NBB*128*192;
  if (tid < n2){
    int nb = tid / (128*192); int r = tid - nb*128*192; int n = r / 192, k = r - n*192;
    w2T[tid] = f2bf(ff_w2[(nb*192 + k)*128 + n]); return;
  }
  tid -= n2;
  const int n3 = NBB*HH*64*32;
  if (tid < n3){
    int nb = tid / (HH*64*32); int r = tid - nb*HH*64*32;
    int h = r >> 11; int r2 = r & 2047; int n = r2 >> 5, k = r2 & 31;
    const float* W = (n < 32) ? Wi : Wf; int nn = n & 31;
    gifT[tid] = f2bf(W[((nb*HH + h)*32 + k)*32 + nn]); return;
  }
  tid -= n3;
  if (tid < n3){
    int nb = tid / (HH*64*32); int r = tid - nb*HH*64*32;
    int h = r >> 11; int r2 = r & 2047; int n = r2 >> 5, k = r2 & 31;
    const float* W = (n < 32) ? Wz : Wo; int nn = n & 31;
    gzoT[tid] = f2bf(W[((nb*HH + h)*32 + k)*32 + nn]); return;
  }
}

// ------- fused LN1 + causal conv + silu + gate projections (one block = one b)
// Phase 1: LN -> xnl (bf16 LDS, + x init when useemb).  Phase 2: conv+silu ->
// xcl.  Phase 3: 4 waves = 4 heads, 64 MFMA each, store gates in scan layout
// [b][h][t>>3][col(128)][t&7].  No xn/xc HBM round trip.
__global__ __launch_bounds__(256) void k_lngates(float* __restrict__ x,
    const int* __restrict__ tok, const float* __restrict__ emb,
    const float* __restrict__ ln1_w, const float* __restrict__ conv_w,
    const float* __restrict__ conv_b, const u16* __restrict__ gifT,
    const u16* __restrict__ gzoT, u16* __restrict__ gates, int nb, int useemb){
  __shared__ u16 xnl[128][136];
  __shared__ u16 xcl[128][136];
  int b = blockIdx.x;
  int wid = threadIdx.x >> 6, l = threadIdx.x & 63;
  // --- phase 1: LN1 (32 rows per wave)
  {
    float2 w = ((const float2*)(ln1_w + nb*128))[l];
    for (int rr = 0; rr < 32; rr++){
      int t = wid*32 + rr;
      const float* src = useemb ? (emb + (size_t)tok[b*TT + t]*128)
                                : (x + (size_t)(b*TT + t)*128);
      float2 v = ((const float2*)src)[l];
      float s  = wsum64(v.x + v.y);
      float sq = wsum64(v.x*v.x + v.y*v.y);
      float mu = s * (1.f/128.f);
      float var = sq * (1.f/128.f) - mu*mu;
      float rs = rsqrtf(var + EPSF);
      float y0 = (v.x - mu)*rs*w.x, y1 = (v.y - mu)*rs*w.y;
      ((u32*)xnl[t])[l] = (u32)f2bf(y0) | ((u32)f2bf(y1) << 16);
      if (useemb) ((float2*)(x + (size_t)(b*TT + t)*128))[l] = v;
    }
  }
  __syncthreads();
  // --- phase 2: causal depthwise conv + silu (64 elems per thread)
  for (int e = threadIdx.x; e < 128*128; e += 256){
    int tt = e >> 7, d = e & 127;
    float s = conv_b[nb*128 + d];
    #pragma unroll
    for (int k = 0; k < 4; k++){
      int t = tt + k - 3;
      if (t >= 0) s += bf2f(xnl[t][d]) * conv_w[(nb*128 + d)*4 + k];
    }
    float sig = 1.f / (1.f + __expf(-s));
    xcl[tt][d] = f2bf(s * sig);
  }
  __syncthreads();
  // --- phase 3: gate MFMAs, wave wid = head
  int h = wid;
  short8 bfr[2][4];
  {
    const u16* B0 = gifT + (size_t)(nb*HH + h)*64*32;
    const u16* B1 = gzoT + (size_t)(nb*HH + h)*64*32;
    #pragma unroll
    for (int jt = 0; jt < 4; jt++){
      bfr[0][jt] = *(const short8*)(B0 + (jt*16 + (l & 15))*32 + (l >> 4)*8);
      bfr[1][jt] = *(const short8*)(B1 + (jt*16 + (l & 15))*32 + (l >> 4)*8);
    }
  }
  u16* gb = gates + (size_t)(b*HH + h)*TT*128;
  #pragma unroll
  for (int z = 0; z < 2; z++){
    #pragma unroll
    for (int rg = 0; rg < 8; rg++){
      const u16* Arow = z ? xnl[rg*16 + (l & 15)] : xcl[rg*16 + (l & 15)];
      short8 a = *(const short8*)(Arow + h*32 + (l >> 4)*8);
      int tt = rg*16 + (l >> 4)*4;          // 4-aligned
      #pragma unroll
      for (int jt = 0; jt < 4; jt++){
        f32x4 acc = {0.f, 0.f, 0.f, 0.f};
        acc = __builtin_amdgcn_mfma_f32_16x16x32_bf16(a, bfr[z][jt], acc, 0, 0, 0);
        int cloc = z*64 + jt*16 + (l & 15);
        s16x4 pk;
        #pragma unroll
        for (int r = 0; r < 4; r++) pk[r] = (short)f2bf(acc[r]);
        *(s16x4*)(gb + ((size_t)(tt >> 3)*128 + cloc)*8 + (tt & 7)) = pk;
      }
    }
  }
}

// ---------------- sLSTM recurrent scan + group-norm + residual ----------------
// one wave per (batch, head); lane l owns gate cols l and l+64 (R6/R11 best form).
__global__ __launch_bounds__(256, 2) void k_scan(const u16* __restrict__ gates,
    const float* __restrict__ Rk, const float* __restrict__ cell_b,
    const float* __restrict__ gn_w, float* __restrict__ x,
    float* __restrict__ dump, int nb){
  int wid = threadIdx.x >> 6, l = threadIdx.x & 63;
  int pair = blockIdx.x * 4 + wid;       // 2048 chains
  int b = pair >> 2, h = pair & 3;
  f32x2 rk[32];
  const float* Rkh = Rk + (size_t)(nb*HH + h)*32*128;
  #pragma unroll
  for (int d = 0; d < 32; d++){
    rk[d].x = Rkh[d*128 + l];
    rk[d].y = Rkh[d*128 + l + 64];
  }
  f32x2 cb = { cell_b[(nb*HH + h)*128 + l], cell_b[(nb*HH + h)*128 + l + 64] };
  int e = l & 31;
  bool lo = (l < 32);
  float gnw = gn_w[nb*128 + h*32 + e];
  float hs = 0.f, cs = 0.f, ns = 0.f, ms = 0.f;
  const u16* gbase = gates + (size_t)(b*HH + h)*TT*128;
  float* xp = lo ? (x + (size_t)(b*TT)*128 + h*32 + e) : (dump + pair*32 + e);
  int xstr = lo ? 128 : 0;
  float xnext = xp[0];
  short8 ga = *(const short8*)(gbase + (size_t)l*8);
  short8 gb = *(const short8*)(gbase + (size_t)(l + 64)*8);
  for (int t8 = 0; t8 < 16; t8++){
    short8 na  = *(const short8*)(gbase + ((size_t)(t8+1)*128 + l)*8);
    short8 nb2 = *(const short8*)(gbase + ((size_t)(t8+1)*128 + l + 64)*8);
    #pragma unroll
    for (int k = 0; k < 8; k++){
      float xcur = xnext;
      xnext = xp[xstr];
      f32x2 acc0 = { bf2f((u16)ga[k]) + cb.x, bf2f((u16)gb[k]) + cb.y };
      f32x2 acc1 = {0.f, 0.f}, acc2 = {0.f, 0.f}, acc3 = {0.f, 0.f};
      #pragma unroll
      for (int d = 0; d < 32; d += 4){
        float h0 = bcastf(hs, d),   h1 = bcastf(hs, d+1);
        float h2 = bcastf(hs, d+2), h3 = bcastf(hs, d+3);
        acc0 = __builtin_elementwise_fma((f32x2){h0,h0}, rk[d],   acc0);
        acc1 = __builtin_elementwise_fma((f32x2){h1,h1}, rk[d+1], acc1);
        acc2 = __builtin_elementwise_fma((f32x2){h2,h2}, rk[d+2], acc2);
        acc3 = __builtin_elementwise_fma((f32x2){h3,h3}, rk[d+3], acc3);
      }
      f32x2 rr = (acc0 + acc1) + (acc2 + acc3);
      float r0 = rr.x, r1 = rr.y;
      float fx = down32(r0);
      float ox = down32(r1);
      float mnew = fmaxf(fx + ms, r0);
      float ig = __builtin_amdgcn_exp2f((r0 - mnew) * LOG2E);
      float fg = __builtin_amdgcn_exp2f((fx + ms - mnew) * LOG2E);
      float e2 = __builtin_amdgcn_exp2f(2.f * LOG2E * r1);
      float th = fmaf(-2.f, __builtin_amdgcn_rcpf(e2 + 1.f), 1.f);
      cs = fmaf(fg, cs, ig * th);
      ns = fmaf(fg, ns, ig);
      ms = mnew;
      float se = __builtin_amdgcn_exp2f(-ox * LOG2E);
      hs = cs * __builtin_amdgcn_rcpf(fmaf(ns, se, ns));
      float s = rsum_rows01(hs);
      float sq = rsum_rows01(hs * hs);
      float mu = bcastf(s, 31) * (1.f/32.f);
      float var = bcastf(sq, 31) * (1.f/32.f) - mu*mu;
      float yn = (hs - mu) * __builtin_amdgcn_rsqf(var + EPSF) * gnw;
      xp[0] = xcur + yn;
      xp += xstr;
    }
    ga = na; gb = nb2;
  }
}

// ---------------- fused LN2 + FFN (R11 exact form) ----------
__global__ __launch_bounds__(512, 4) void k_ffn(float* __restrict__ x,
    const float* __restrict__ ln2_w, const u16* __restrict__ w1T,
    const float* __restrict__ ff_b1, const u16* __restrict__ w2T,
    const float* __restrict__ ff_b2, int nb){
  __shared__ u16 xln[64][136];
  __shared__ u16 hbuf[64][392];
  int m0 = blockIdx.x * 64;
  int w = threadIdx.x >> 6, l = threadIdx.x & 63;
  short8 w1f[3][4];
  const u16* W1 = w1T + (size_t)nb*384*128;
  #pragma unroll
  for (int j = 0; j < 3; j++)
    #pragma unroll
    for (int c = 0; c < 4; c++)
      w1f[j][c] = *(const short8*)(W1 + (size_t)((3*w + j)*16 + (l & 15))*128 + c*32 + (l >> 4)*8);
  short8 w2f[6];
  const u16* W2 = w2T + (size_t)nb*128*192;
  #pragma unroll
  for (int c = 0; c < 6; c++)
    w2f[c] = *(const short8*)(W2 + (size_t)(w*16 + (l & 15))*192 + c*32 + (l >> 4)*8);
  float2 lw = ((const float2*)(ln2_w + nb*128))[l];
  #pragma unroll
  for (int rr = 0; rr < 8; rr++){
    int row = w*8 + rr;
    float2 v = ((const float2*)(x + (size_t)(m0 + row)*128))[l];
    float s  = wsum64(v.x + v.y);
    float sq = wsum64(v.x*v.x + v.y*v.y);
    float mu = s * (1.f/128.f);
    float var = sq * (1.f/128.f) - mu*mu;
    float rs = rsqrtf(var + EPSF);
    ((u32*)xln[row])[l] = (u32)f2bf((v.x - mu)*rs*lw.x)
                        | ((u32)f2bf((v.y - mu)*rs*lw.y) << 16);
  }
  __syncthreads();
  #pragma unroll
  for (int rg = 0; rg < 4; rg++){
    short8 a[4];
    #pragma unroll
    for (int c = 0; c < 4; c++)
      a[c] = *(const short8*)(&xln[rg*16 + (l & 15)][c*32 + (l >> 4)*8]);
    #pragma unroll
    for (int j = 0; j < 3; j++){
      f32x4 acc = {0.f, 0.f, 0.f, 0.f};
      #pragma unroll
      for (int c = 0; c < 4; c++)
        acc = __builtin_amdgcn_mfma_f32_16x16x32_bf16(a[c], w1f[j][c], acc, 0, 0, 0);
      int col = (3*w + j)*16 + (l & 15);
      float bb = ff_b1[nb*384 + col];
      #pragma unroll
      for (int r = 0; r < 4; r++){
        int row = rg*16 + (l >> 4)*4 + r;
        hbuf[row][col] = f2bf(acc[r] + bb);
      }
    }
  }
  __syncthreads();
  {
    int row = threadIdx.x >> 3;
    int k0 = (threadIdx.x & 7) * 24;
    #pragma unroll
    for (int j2 = 0; j2 < 24; j2++){
      int k = k0 + j2;
      float gt = bf2f(hbuf[row][k]);
      float u = bf2f(hbuf[row][k + 192]);
      hbuf[row][k] = f2bf(gelu_fast(gt) * u);
    }
  }
  __syncthreads();
  #pragma unroll
  for (int rg = 0; rg < 4; rg++){
    f32x4 acc = {0.f, 0.f, 0.f, 0.f};
    #pragma unroll
    for (int c = 0; c < 6; c++){
      short8 a = *(const short8*)(&hbuf[rg*16 + (l & 15)][c*32 + (l >> 4)*8]);
      acc = __builtin_amdgcn_mfma_f32_16x16x32_bf16(a, w2f[c], acc, 0, 0, 0);
    }
    int col = w*16 + (l & 15);
    float bb = ff_b2[nb*128 + col];
    #pragma unroll
    for (int r = 0; r < 4; r++){
      int row = m0 + rg*16 + (l >> 4)*4 + r;
      x[(size_t)row*128 + col] += acc[r] + bb;
    }
  }
}

// ---------------- post-LN + mean-pool + classifier ----------------
__global__ __launch_bounds__(256) void k_pool_cls(const float* __restrict__ x,
    const float* __restrict__ pw, const float* __restrict__ w1,
    const float* __restrict__ b1, const float* __restrict__ w2,
    const float* __restrict__ b2, float* __restrict__ out){
  __shared__ float red[4][128];
  __shared__ float pooled[128];
  __shared__ float h1s[64];
  int b = blockIdx.x;
  int wid = threadIdx.x >> 6, l = threadIdx.x & 63;
  float2 w = ((const float2*)pw)[l];
  float ax = 0.f, ay = 0.f;
  for (int t = wid; t < TT; t += 4){
    float2 v = ((const float2*)(x + (size_t)(b*TT + t)*128))[l];
    float s  = wsum64(v.x + v.y);
    float sq = wsum64(v.x*v.x + v.y*v.y);
    float mu = s * (1.f/128.f);
    float var = sq * (1.f/128.f) - mu*mu;
    float rs = rsqrtf(var + EPSF);
    ax += (v.x - mu)*rs*w.x;
    ay += (v.y - mu)*rs*w.y;
  }
  red[wid][2*l] = ax; red[wid][2*l+1] = ay;
  __syncthreads();
  if (threadIdx.x < 128){
    int d = threadIdx.x;
    pooled[d] = (red[0][d] + red[1][d] + red[2][d] + red[3][d]) * (1.f/128.f);
  }
  __syncthreads();
  if (threadIdx.x < 64){
    int j = threadIdx.x;
    float s = b1[j];
    for (int d = 0; d < 128; d++) s += pooled[d] * w1[d*64 + j];
    h1s[j] = fmaxf(s, 0.f);
  }
  __syncthreads();
  if (threadIdx.x < 2){
    int j = threadIdx.x;
    float s = b2[j];
    for (int k = 0; k < 64; k++) s += h1s[k] * w2[k*2 + j];
    out[b*2 + j] = s;
  }
}

extern "C" void kernel_launch(void* const* d_in, const int* in_sizes, int n_in,
                              void* d_out, int out_size, void* d_ws, size_t ws_size,
                              hipStream_t stream){
  const int*   tok    = (const int*)d_in[0];
  const float* emb    = (const float*)d_in[1];
  const float* ln1_w  = (const float*)d_in[2];
  const float* conv_w = (const float*)d_in[3];
  const float* conv_b = (const float*)d_in[4];
  const float* Wi     = (const float*)d_in[5];
  const float* Wf     = (const float*)d_in[6];
  const float* Wz     = (const float*)d_in[7];
  const float* Wo     = (const float*)d_in[8];
  const float* Rk     = (const float*)d_in[9];
  const float* cell_b = (const float*)d_in[10];
  const float* gn_w   = (const float*)d_in[11];
  const float* ln2_w  = (const float*)d_in[12];
  const float* ff_w1  = (const float*)d_in[13];
  const float* ff_b1  = (const float*)d_in[14];
  const float* ff_w2  = (const float*)d_in[15];
  const float* ff_b2  = (const float*)d_in[16];
  const float* postw  = (const float*)d_in[17];
  const float* cw1    = (const float*)d_in[18];
  const float* cb1    = (const float*)d_in[19];
  const float* cw2    = (const float*)d_in[20];
  const float* cb2    = (const float*)d_in[21];
  float* out = (float*)d_out;

  char* ws = (char*)d_ws;
  size_t off = 0;
  float* x      = (float*)(ws + off); off += (size_t)BT*128*4;
  float* dump   = (float*)(ws + off); off += (size_t)2048*32*4;
  u16*   gates  = (u16*)(ws + off);   off += (size_t)BT*512*2;
  u16*   w1T    = (u16*)(ws + off);   off += (size_t)NBB*384*128*2;
  u16*   w2T    = (u16*)(ws + off);   off += (size_t)NBB*128*192*2;
  u16*   gifT   = (u16*)(ws + off);   off += (size_t)NBB*HH*64*32*2;
  u16*   gzoT   = (u16*)(ws + off);   off += (size_t)NBB*HH*64*32*2;

  k_convert<<<704, 256, 0, stream>>>(ff_w1, ff_w2, Wi, Wf, Wz, Wo, w1T, w2T, gifT, gzoT);
  for (int nb = 0; nb < NBB; nb++){
    k_lngates<<<BB, 256, 0, stream>>>(x, tok, emb, ln1_w, conv_w, conv_b,
                                      gifT, gzoT, gates, nb, nb == 0 ? 1 : 0);
    k_scan<<<512, 256, 0, stream>>>(gates, Rk, cell_b, gn_w, x, dump, nb);
    k_ffn<<<BT/64, 512, 0, stream>>>(x, ln2_w, w1T, ff_b1, w2T, ff_b2, nb);
  }
  k_pool_cls<<<BB, 256, 0, stream>>>(x, postw, cw1, cb1, cw2, cb2, out);
}

// Round 15
// 297.699 us; speedup vs baseline: 1.1449x; 1.1449x over previous
//
#include <hip/hip_runtime.h>

typedef unsigned short u16;
typedef unsigned int u32;
typedef __attribute__((ext_vector_type(8))) short short8;
typedef __attribute__((ext_vector_type(4))) short s16x4;
typedef __attribute__((ext_vector_type(4))) float f32x4;
typedef __attribute__((ext_vector_type(2))) float f32x2;
typedef __attribute__((ext_vector_type(2))) int i32x2;

#define BB 512
#define TT 128
#define DD 128
#define HH 4
#define NBB 2
#define BT (BB*TT)
#define EPSF 1e-5f
#define LOG2E 1.4426950408889634f

__device__ __forceinline__ float bf2f(u16 u){ return __uint_as_float(((u32)u) << 16); }
__device__ __forceinline__ u16 f2bf(float f){
  u32 x = __float_as_uint(f);
  u32 r = x + 0x7fffu + ((x >> 16) & 1u);
  return (u16)(r >> 16);
}
__device__ __forceinline__ float bcastf(float v, int lane){
  return __uint_as_float(__builtin_amdgcn_readlane(__float_as_uint(v), lane));
}
// gelu (tanh approx) with rcp/exp2 only
__device__ __forceinline__ float gelu_fast(float x){
  float u = 0.7978845608028654f * (x + 0.044715f * x * x * x);
  float e2 = __builtin_amdgcn_exp2f(2.f * LOG2E * u);
  return x - x * __builtin_amdgcn_rcpf(e2 + 1.f);
}
#define DPP_ADD(v, ctrl, rmask, bc) \
  v += __int_as_float(__builtin_amdgcn_update_dpp(0, __float_as_int(v), (ctrl), (rmask), 0xf, (bc)))
// full-wave (64-lane) sum via DPP, broadcast to all lanes through SGPR
__device__ __forceinline__ float wsum64(float v){
  DPP_ADD(v, 0x111, 0xf, true);
  DPP_ADD(v, 0x112, 0xf, true);
  DPP_ADD(v, 0x114, 0xf, true);
  DPP_ADD(v, 0x118, 0xf, true);
  DPP_ADD(v, 0x142, 0xa, false);
  DPP_ADD(v, 0x143, 0xc, false);
  return bcastf(v, 63);
}
// sum over lanes 0..31; total lands in lane 31
__device__ __forceinline__ float rsum_rows01(float v){
  DPP_ADD(v, 0x111, 0xf, true);
  DPP_ADD(v, 0x112, 0xf, true);
  DPP_ADD(v, 0x114, 0xf, true);
  DPP_ADD(v, 0x118, 0xf, true);
  DPP_ADD(v, 0x142, 0xa, false);
  return v;
}
// lanes<32 receive v from lane+32 (VALU permlane32_swap; no LDS).
__device__ __forceinline__ float down32(float v){
  i32x2 r = __builtin_amdgcn_permlane32_swap(__float_as_int(v), __float_as_int(v), false, false);
  return __int_as_float(r.y);
}

// ---------------- weight conversion to bf16 (transposed for MFMA B-frags) ----
__global__ __launch_bounds__(256) void k_convert(
    const float* __restrict__ ff_w1, const float* __restrict__ ff_w2,
    const float* __restrict__ Wi, const float* __restrict__ Wf,
    const float* __restrict__ Wz, const float* __restrict__ Wo,
    u16* __restrict__ w1T, u16* __restrict__ w2T,
    u16* __restrict__ gifT, u16* __restrict__ gzoT){
  int tid = blockIdx.x * 256 + threadIdx.x;
  const int n1 = NBB*384*128;
  if (tid < n1){
    int nb = tid / (384*128); int r = tid - nb*384*128; int n = r >> 7, k = r & 127;
    w1T[tid] = f2bf(ff_w1[(nb*128 + k)*384 + n]); return;
  }
  tid -= n1;
  const int n2 = NBB*128*192;
  if (tid < n2){
    int nb = tid / (128*192); int r = tid - nb*128*192; int n = r / 192, k = r - n*192;
    w2T[tid] = f2bf(ff_w2[(nb*192 + k)*128 + n]); return;
  }
  tid -= n2;
  const int n3 = NBB*HH*64*32;
  if (tid < n3){
    int nb = tid / (HH*64*32); int r = tid - nb*HH*64*32;
    int h = r >> 11; int r2 = r & 2047; int n = r2 >> 5, k = r2 & 31;
    const float* W = (n < 32) ? Wi : Wf; int nn = n & 31;
    gifT[tid] = f2bf(W[((nb*HH + h)*32 + k)*32 + nn]); return;
  }
  tid -= n3;
  if (tid < n3){
    int nb = tid / (HH*64*32); int r = tid - nb*HH*64*32;
    int h = r >> 11; int r2 = r & 2047; int n = r2 >> 5, k = r2 & 31;
    const float* W = (n < 32) ? Wz : Wo; int nn = n & 31;
    gzoT[tid] = f2bf(W[((nb*HH + h)*32 + k)*32 + nn]); return;
  }
}

// ---------------- LN1 + causal depthwise conv + silu ----------------
// useemb: read rows from emb[tok] (nb=0) and also materialize x; else read x.
__global__ __launch_bounds__(256) void k_lnconv(float* __restrict__ x,
    const int* __restrict__ tok, const float* __restrict__ emb,
    const float* __restrict__ ln1_w, const float* __restrict__ conv_w,
    const float* __restrict__ conv_b, u16* __restrict__ xn_bf,
    u16* __restrict__ xc_bf, int nb, int useemb){
  __shared__ float lnbuf[35][128];
  int b = blockIdx.x >> 2, tile = blockIdx.x & 3;
  int t0 = tile * 32;
  int wid = threadIdx.x >> 6, l = threadIdx.x & 63;
  for (int tt = wid; tt < 35; tt += 4){
    int t = t0 - 3 + tt;
    if (t < 0){
      lnbuf[tt][2*l] = 0.f; lnbuf[tt][2*l+1] = 0.f;
    } else {
      const float* src = useemb ? (emb + (size_t)tok[b*TT + t]*128)
                                : (x + (size_t)(b*TT + t)*128);
      float2 v = ((const float2*)src)[l];
      float s  = wsum64(v.x + v.y);
      float sq = wsum64(v.x*v.x + v.y*v.y);
      float mu = s * (1.f/128.f);
      float var = sq * (1.f/128.f) - mu*mu;
      float rs = rsqrtf(var + EPSF);
      float2 w = ((const float2*)(ln1_w + nb*128))[l];
      float y0 = (v.x - mu)*rs*w.x, y1 = (v.y - mu)*rs*w.y;
      lnbuf[tt][2*l] = y0; lnbuf[tt][2*l+1] = y1;
      if (tt >= 3){
        u32 pk = (u32)f2bf(y0) | ((u32)f2bf(y1) << 16);
        ((u32*)(xn_bf + (size_t)(b*TT + t)*128))[l] = pk;
        if (useemb) ((float2*)(x + (size_t)(b*TT + t)*128))[l] = v;
      }
    }
  }
  __syncthreads();
  for (int e = threadIdx.x; e < 32*128; e += 256){
    int tt = e >> 7, d = e & 127;
    float s = conv_b[nb*128 + d];
    #pragma unroll
    for (int k = 0; k < 4; k++)
      s += lnbuf[tt + k][d] * conv_w[(nb*128 + d)*4 + k];
    float sig = 1.f / (1.f + __expf(-s));
    xc_bf[(size_t)(b*TT + t0 + tt)*128 + d] = f2bf(s * sig);
  }
}

// ---------------- gate projections (MFMA) ----------------
// grid BT/64; wave wid = head h; handles z=0,1 and 4 row-groups (32 MFMA/wave)
// gates layout: [b][h][t>>3][col(128)][t&7]
__global__ __launch_bounds__(256) void k_gates(const u16* __restrict__ xc_bf,
    const u16* __restrict__ xn_bf, const u16* __restrict__ gifT,
    const u16* __restrict__ gzoT, u16* __restrict__ gates, int nb){
  int m0 = blockIdx.x * 64;
  int b = m0 >> 7;
  int t00 = m0 & 127;
  int h = threadIdx.x >> 6, l = threadIdx.x & 63;
  short8 bfr[2][4];
  {
    const u16* B0 = gifT + (size_t)(nb*HH + h)*64*32;
    const u16* B1 = gzoT + (size_t)(nb*HH + h)*64*32;
    #pragma unroll
    for (int jt = 0; jt < 4; jt++){
      bfr[0][jt] = *(const short8*)(B0 + (jt*16 + (l & 15))*32 + (l >> 4)*8);
      bfr[1][jt] = *(const short8*)(B1 + (jt*16 + (l & 15))*32 + (l >> 4)*8);
    }
  }
  u16* gb = gates + (size_t)(b*HH + h)*TT*128;
  #pragma unroll
  for (int z = 0; z < 2; z++){
    const u16* A = z ? xn_bf : xc_bf;
    #pragma unroll
    for (int rg = 0; rg < 4; rg++){
      int r0 = m0 + rg*16;
      short8 a = *(const short8*)(A + (size_t)(r0 + (l & 15))*128 + h*32 + (l >> 4)*8);
      int tt = t00 + rg*16 + (l >> 4)*4;          // 4-aligned
      #pragma unroll
      for (int jt = 0; jt < 4; jt++){
        f32x4 acc = {0.f, 0.f, 0.f, 0.f};
        acc = __builtin_amdgcn_mfma_f32_16x16x32_bf16(a, bfr[z][jt], acc, 0, 0, 0);
        int cloc = z*64 + jt*16 + (l & 15);
        s16x4 pk;
        #pragma unroll
        for (int r = 0; r < 4; r++) pk[r] = (short)f2bf(acc[r]);
        *(s16x4*)(gb + ((size_t)(tt >> 3)*128 + cloc)*8 + (tt & 7)) = pk;
      }
    }
  }
}

// ---------------- sLSTM recurrent scan + group-norm + residual ----------------
// one wave per (batch, head); lane l owns gate cols l and l+64 (R6/R11 form).
// lanes<32: (ir, zr); lanes>=32: (fr, og). No LDS/DS ops, no divergence.
// x residual prefetched 4 steps deep (per-step dependent load > HBM latency).
__global__ __launch_bounds__(256, 2) void k_scan(const u16* __restrict__ gates,
    const float* __restrict__ Rk, const float* __restrict__ cell_b,
    const float* __restrict__ gn_w, float* __restrict__ x,
    float* __restrict__ dump, int nb){
  int wid = threadIdx.x >> 6, l = threadIdx.x & 63;
  int pair = blockIdx.x * 4 + wid;       // 2048 chains
  int b = pair >> 2, h = pair & 3;
  f32x2 rk[32];
  const float* Rkh = Rk + (size_t)(nb*HH + h)*32*128;
  #pragma unroll
  for (int d = 0; d < 32; d++){
    rk[d].x = Rkh[d*128 + l];
    rk[d].y = Rkh[d*128 + l + 64];
  }
  f32x2 cb = { cell_b[(nb*HH + h)*128 + l], cell_b[(nb*HH + h)*128 + l + 64] };
  int e = l & 31;
  bool lo = (l < 32);
  float gnw = gn_w[nb*128 + h*32 + e];
  float hs = 0.f, cs = 0.f, ns = 0.f, ms = 0.f;
  const u16* gbase = gates + (size_t)(b*HH + h)*TT*128;
  // always-exec residual pointers: hi lanes use a per-wave dump row (stride 0)
  float* xp = lo ? (x + (size_t)(b*TT)*128 + h*32 + e) : (dump + pair*32 + e);
  int xstr = lo ? 128 : 0;
  // 4-deep prefetch ring for the residual stream (overreads 4 rows at end — ws mapped)
  float xq0 = xp[0];
  float xq1 = xp[xstr];
  float xq2 = xp[2*xstr];
  float xq3 = xp[3*xstr];
  short8 ga = *(const short8*)(gbase + (size_t)l*8);
  short8 gb = *(const short8*)(gbase + (size_t)(l + 64)*8);
  for (int t8 = 0; t8 < 16; t8++){
    // prefetch next 8 steps' gates (1KB-coalesced; overreads at end — ws mapped)
    short8 na  = *(const short8*)(gbase + ((size_t)(t8+1)*128 + l)*8);
    short8 nb2 = *(const short8*)(gbase + ((size_t)(t8+1)*128 + l + 64)*8);
    #pragma unroll
    for (int k = 0; k < 8; k++){
      float xcur = xq0;
      xq0 = xq1; xq1 = xq2; xq2 = xq3;
      xq3 = xp[4*xstr];                  // load for step t+4
      f32x2 acc0 = { bf2f((u16)ga[k]) + cb.x, bf2f((u16)gb[k]) + cb.y };
      f32x2 acc1 = {0.f, 0.f}, acc2 = {0.f, 0.f}, acc3 = {0.f, 0.f};
      #pragma unroll
      for (int d = 0; d < 32; d += 4){
        float h0 = bcastf(hs, d),   h1 = bcastf(hs, d+1);
        float h2 = bcastf(hs, d+2), h3 = bcastf(hs, d+3);
        acc0 = __builtin_elementwise_fma((f32x2){h0,h0}, rk[d],   acc0);
        acc1 = __builtin_elementwise_fma((f32x2){h1,h1}, rk[d+1], acc1);
        acc2 = __builtin_elementwise_fma((f32x2){h2,h2}, rk[d+2], acc2);
        acc3 = __builtin_elementwise_fma((f32x2){h3,h3}, rk[d+3], acc3);
      }
      f32x2 rr = (acc0 + acc1) + (acc2 + acc3);
      float r0 = rr.x, r1 = rr.y;          // lanes<32: ir, zr ; lanes>=32: fr, og
      float fx = down32(r0);               // lanes<32 get fr[e]
      float ox = down32(r1);               // lanes<32 get og[e]
      // gating — valid in lanes<32; upper lanes compute garbage (dump-only)
      float mnew = fmaxf(fx + ms, r0);
      float ig = __builtin_amdgcn_exp2f((r0 - mnew) * LOG2E);
      float fg = __builtin_amdgcn_exp2f((fx + ms - mnew) * LOG2E);
      float e2 = __builtin_amdgcn_exp2f(2.f * LOG2E * r1);
      float th = fmaf(-2.f, __builtin_amdgcn_rcpf(e2 + 1.f), 1.f);   // tanh(zr)
      cs = fmaf(fg, cs, ig * th);
      ns = fmaf(fg, ns, ig);
      ms = mnew;
      // hs = cs * sigmoid(og) / ns  with one rcp
      float se = __builtin_amdgcn_exp2f(-ox * LOG2E);
      hs = cs * __builtin_amdgcn_rcpf(fmaf(ns, se, ns));
      // group norm over lanes 0..31 via DPP (no LDS)
      float s = rsum_rows01(hs);
      float sq = rsum_rows01(hs * hs);
      float mu = bcastf(s, 31) * (1.f/32.f);
      float var = bcastf(sq, 31) * (1.f/32.f) - mu*mu;
      float yn = (hs - mu) * __builtin_amdgcn_rsqf(var + EPSF) * gnw;
      xp[0] = xcur + yn;
      xp += xstr;
    }
    ga = na; gb = nb2;
  }
}

// ---------------- fused LN2 + FFN (N-partitioned, W loaded once/block) -------
__global__ __launch_bounds__(512, 4) void k_ffn(float* __restrict__ x,
    const float* __restrict__ ln2_w, const u16* __restrict__ w1T,
    const float* __restrict__ ff_b1, const u16* __restrict__ w2T,
    const float* __restrict__ ff_b2, int nb){
  __shared__ u16 xln[64][136];
  __shared__ u16 hbuf[64][392];
  int m0 = blockIdx.x * 64;
  int w = threadIdx.x >> 6, l = threadIdx.x & 63;
  short8 w1f[3][4];
  const u16* W1 = w1T + (size_t)nb*384*128;
  #pragma unroll
  for (int j = 0; j < 3; j++)
    #pragma unroll
    for (int c = 0; c < 4; c++)
      w1f[j][c] = *(const short8*)(W1 + (size_t)((3*w + j)*16 + (l & 15))*128 + c*32 + (l >> 4)*8);
  short8 w2f[6];
  const u16* W2 = w2T + (size_t)nb*128*192;
  #pragma unroll
  for (int c = 0; c < 6; c++)
    w2f[c] = *(const short8*)(W2 + (size_t)(w*16 + (l & 15))*192 + c*32 + (l >> 4)*8);
  float2 lw = ((const float2*)(ln2_w + nb*128))[l];
  #pragma unroll
  for (int rr = 0; rr < 8; rr++){
    int row = w*8 + rr;
    float2 v = ((const float2*)(x + (size_t)(m0 + row)*128))[l];
    float s  = wsum64(v.x + v.y);
    float sq = wsum64(v.x*v.x + v.y*v.y);
    float mu = s * (1.f/128.f);
    float var = sq * (1.f/128.f) - mu*mu;
    float rs = rsqrtf(var + EPSF);
    ((u32*)xln[row])[l] = (u32)f2bf((v.x - mu)*rs*lw.x)
                        | ((u32)f2bf((v.y - mu)*rs*lw.y) << 16);
  }
  __syncthreads();
  #pragma unroll
  for (int rg = 0; rg < 4; rg++){
    short8 a[4];
    #pragma unroll
    for (int c = 0; c < 4; c++)
      a[c] = *(const short8*)(&xln[rg*16 + (l & 15)][c*32 + (l >> 4)*8]);
    #pragma unroll
    for (int j = 0; j < 3; j++){
      f32x4 acc = {0.f, 0.f, 0.f, 0.f};
      #pragma unroll
      for (int c = 0; c < 4; c++)
        acc = __builtin_amdgcn_mfma_f32_16x16x32_bf16(a[c], w1f[j][c], acc, 0, 0, 0);
      int col = (3*w + j)*16 + (l & 15);
      float bb = ff_b1[nb*384 + col];
      #pragma unroll
      for (int r = 0; r < 4; r++){
        int row = rg*16 + (l >> 4)*4 + r;
        hbuf[row][col] = f2bf(acc[r] + bb);
      }
    }
  }
  __syncthreads();
  {
    int row = threadIdx.x >> 3;
    int k0 = (threadIdx.x & 7) * 24;
    #pragma unroll
    for (int j2 = 0; j2 < 24; j2++){
      int k = k0 + j2;
      float gt = bf2f(hbuf[row][k]);
      float u = bf2f(hbuf[row][k + 192]);
      hbuf[row][k] = f2bf(gelu_fast(gt) * u);
    }
  }
  __syncthreads();
  #pragma unroll
  for (int rg = 0; rg < 4; rg++){
    f32x4 acc = {0.f, 0.f, 0.f, 0.f};
    #pragma unroll
    for (int c = 0; c < 6; c++){
      short8 a = *(const short8*)(&hbuf[rg*16 + (l & 15)][c*32 + (l >> 4)*8]);
      acc = __builtin_amdgcn_mfma_f32_16x16x32_bf16(a, w2f[c], acc, 0, 0, 0);
    }
    int col = w*16 + (l & 15);
    float bb = ff_b2[nb*128 + col];
    #pragma unroll
    for (int r = 0; r < 4; r++){
      int row = m0 + rg*16 + (l >> 4)*4 + r;
      x[(size_t)row*128 + col] += acc[r] + bb;
    }
  }
}

// ---------------- post-LN + mean-pool + classifier ----------------
__global__ __launch_bounds__(256) void k_pool_cls(const float* __restrict__ x,
    const float* __restrict__ pw, const float* __restrict__ w1,
    const float* __restrict__ b1, const float* __restrict__ w2,
    const float* __restrict__ b2, float* __restrict__ out){
  __shared__ float red[4][128];
  __shared__ float pooled[128];
  __shared__ float h1s[64];
  int b = blockIdx.x;
  int wid = threadIdx.x >> 6, l = threadIdx.x & 63;
  float2 w = ((const float2*)pw)[l];
  float ax = 0.f, ay = 0.f;
  for (int t = wid; t < TT; t += 4){
    float2 v = ((const float2*)(x + (size_t)(b*TT + t)*128))[l];
    float s  = wsum64(v.x + v.y);
    float sq = wsum64(v.x*v.x + v.y*v.y);
    float mu = s * (1.f/128.f);
    float var = sq * (1.f/128.f) - mu*mu;
    float rs = rsqrtf(var + EPSF);
    ax += (v.x - mu)*rs*w.x;
    ay += (v.y - mu)*rs*w.y;
  }
  red[wid][2*l] = ax; red[wid][2*l+1] = ay;
  __syncthreads();
  if (threadIdx.x < 128){
    int d = threadIdx.x;
    pooled[d] = (red[0][d] + red[1][d] + red[2][d] + red[3][d]) * (1.f/128.f);
  }
  __syncthreads();
  if (threadIdx.x < 64){
    int j = threadIdx.x;
    float s = b1[j];
    for (int d = 0; d < 128; d++) s += pooled[d] * w1[d*64 + j];
    h1s[j] = fmaxf(s, 0.f);
  }
  __syncthreads();
  if (threadIdx.x < 2){
    int j = threadIdx.x;
    float s = b2[j];
    for (int k = 0; k < 64; k++) s += h1s[k] * w2[k*2 + j];
    out[b*2 + j] = s;
  }
}

extern "C" void kernel_launch(void* const* d_in, const int* in_sizes, int n_in,
                              void* d_out, int out_size, void* d_ws, size_t ws_size,
                              hipStream_t stream){
  const int*   tok    = (const int*)d_in[0];
  const float* emb    = (const float*)d_in[1];
  const float* ln1_w  = (const float*)d_in[2];
  const float* conv_w = (const float*)d_in[3];
  const float* conv_b = (const float*)d_in[4];
  const float* Wi     = (const float*)d_in[5];
  const float* Wf     = (const float*)d_in[6];
  const float* Wz     = (const float*)d_in[7];
  const float* Wo     = (const float*)d_in[8];
  const float* Rk     = (const float*)d_in[9];
  const float* cell_b = (const float*)d_in[10];
  const float* gn_w   = (const float*)d_in[11];
  const float* ln2_w  = (const float*)d_in[12];
  const float* ff_w1  = (const float*)d_in[13];
  const float* ff_b1  = (const float*)d_in[14];
  const float* ff_w2  = (const float*)d_in[15];
  const float* ff_b2  = (const float*)d_in[16];
  const float* postw  = (const float*)d_in[17];
  const float* cw1    = (const float*)d_in[18];
  const float* cb1    = (const float*)d_in[19];
  const float* cw2    = (const float*)d_in[20];
  const float* cb2    = (const float*)d_in[21];
  float* out = (float*)d_out;

  char* ws = (char*)d_ws;
  size_t off = 0;
  float* x      = (float*)(ws + off); off += (size_t)BT*128*4;
  u16*   xn_bf  = (u16*)(ws + off);   off += (size_t)BT*128*2;
  u16*   xc_bf  = (u16*)(ws + off);   off += (size_t)BT*128*2;
  u16*   gates  = (u16*)(ws + off);   off += (size_t)BT*512*2;
  u16*   w1T    = (u16*)(ws + off);   off += (size_t)NBB*384*128*2;
  u16*   w2T    = (u16*)(ws + off);   off += (size_t)NBB*128*192*2;
  u16*   gifT   = (u16*)(ws + off);   off += (size_t)NBB*HH*64*32*2;
  u16*   gzoT   = (u16*)(ws + off);   off += (size_t)NBB*HH*64*32*2;
  float* dump   = (float*)xn_bf;      // dead during k_scan; 256KB used

  k_convert<<<704, 256, 0, stream>>>(ff_w1, ff_w2, Wi, Wf, Wz, Wo, w1T, w2T, gifT, gzoT);
  for (int nb = 0; nb < NBB; nb++){
    k_lnconv<<<BB*4, 256, 0, stream>>>(x, tok, emb, ln1_w, conv_w, conv_b,
                                       xn_bf, xc_bf, nb, nb == 0 ? 1 : 0);
    k_gates<<<BT/64, 256, 0, stream>>>(xc_bf, xn_bf, gifT, gzoT, gates, nb);
    k_scan<<<512, 256, 0, stream>>>(gates, Rk, cell_b, gn_w, x, dump, nb);
    k_ffn<<<BT/64, 512, 0, stream>>>(x, ln2_w, w1T, ff_b1, w2T, ff_b2, nb);
  }
  k_pool_cls<<<BB, 256, 0, stream>>>(x, postw, cw1, cb1, cw2, cb2, out);
}

// Round 16
// 273.292 us; speedup vs baseline: 1.2472x; 1.0893x over previous
//
#include <hip/hip_runtime.h>

typedef unsigned short u16;
typedef unsigned int u32;
typedef __attribute__((ext_vector_type(8))) short short8;
typedef __attribute__((ext_vector_type(4))) short s16x4;
typedef __attribute__((ext_vector_type(4))) float f32x4;
typedef __attribute__((ext_vector_type(2))) float f32x2;
typedef __attribute__((ext_vector_type(2))) int i32x2;

#define BB 512
#define TT 128
#define DD 128
#define HH 4
#define NBB 2
#define BT (BB*TT)
#define EPSF 1e-5f
#define LOG2E 1.4426950408889634f

__device__ __forceinline__ float bf2f(u16 u){ return __uint_as_float(((u32)u) << 16); }
__device__ __forceinline__ u16 f2bf(float f){
  u32 x = __float_as_uint(f);
  u32 r = x + 0x7fffu + ((x >> 16) & 1u);
  return (u16)(r >> 16);
}
__device__ __forceinline__ float bcastf(float v, int lane){
  return __uint_as_float(__builtin_amdgcn_readlane(__float_as_uint(v), lane));
}
// gelu (tanh approx) with rcp/exp2 only
__device__ __forceinline__ float gelu_fast(float x){
  float u = 0.7978845608028654f * (x + 0.044715f * x * x * x);
  float e2 = __builtin_amdgcn_exp2f(2.f * LOG2E * u);
  return x - x * __builtin_amdgcn_rcpf(e2 + 1.f);
}
#define DPP_ADD(v, ctrl, rmask, bc) \
  v += __int_as_float(__builtin_amdgcn_update_dpp(0, __float_as_int(v), (ctrl), (rmask), 0xf, (bc)))
// full-wave (64-lane) sum via DPP, broadcast to all lanes through SGPR
__device__ __forceinline__ float wsum64(float v){
  DPP_ADD(v, 0x111, 0xf, true);
  DPP_ADD(v, 0x112, 0xf, true);
  DPP_ADD(v, 0x114, 0xf, true);
  DPP_ADD(v, 0x118, 0xf, true);
  DPP_ADD(v, 0x142, 0xa, false);
  DPP_ADD(v, 0x143, 0xc, false);
  return bcastf(v, 63);
}
// sum over lanes 0..31; total lands in lane 31
__device__ __forceinline__ float rsum_rows01(float v){
  DPP_ADD(v, 0x111, 0xf, true);
  DPP_ADD(v, 0x112, 0xf, true);
  DPP_ADD(v, 0x114, 0xf, true);
  DPP_ADD(v, 0x118, 0xf, true);
  DPP_ADD(v, 0x142, 0xa, false);
  return v;
}
// lanes<32 receive v from lane+32 (VALU permlane32_swap; no LDS).
__device__ __forceinline__ float down32(float v){
  i32x2 r = __builtin_amdgcn_permlane32_swap(__float_as_int(v), __float_as_int(v), false, false);
  return __int_as_float(r.y);
}

// ---------------- weight conversion to bf16 (transposed for MFMA B-frags) ----
__global__ __launch_bounds__(256) void k_convert(
    const float* __restrict__ ff_w1, const float* __restrict__ ff_w2,
    const float* __restrict__ Wi, const float* __restrict__ Wf,
    const float* __restrict__ Wz, const float* __restrict__ Wo,
    u16* __restrict__ w1T, u16* __restrict__ w2T,
    u16* __restrict__ gifT, u16* __restrict__ gzoT){
  int tid = blockIdx.x * 256 + threadIdx.x;
  const int n1 = NBB*384*128;
  if (tid < n1){
    int nb = tid / (384*128); int r = tid - nb*384*128; int n = r >> 7, k = r & 127;
    w1T[tid] = f2bf(ff_w1[(nb*128 + k)*384 + n]); return;
  }
  tid -= n1;
  const int n2 = NBB*128*192;
  if (tid < n2){
    int nb = tid / (128*192); int r = tid - nb*128*192; int n = r / 192, k = r - n*192;
    w2T[tid] = f2bf(ff_w2[(nb*192 + k)*128 + n]); return;
  }
  tid -= n2;
  const int n3 = NBB*HH*64*32;
  if (tid < n3){
    int nb = tid / (HH*64*32); int r = tid - nb*HH*64*32;
    int h = r >> 11; int r2 = r & 2047; int n = r2 >> 5, k = r2 & 31;
    const float* W = (n < 32) ? Wi : Wf; int nn = n & 31;
    gifT[tid] = f2bf(W[((nb*HH + h)*32 + k)*32 + nn]); return;
  }
  tid -= n3;
  if (tid < n3){
    int nb = tid / (HH*64*32); int r = tid - nb*HH*64*32;
    int h = r >> 11; int r2 = r & 2047; int n = r2 >> 5, k = r2 & 31;
    const float* W = (n < 32) ? Wz : Wo; int nn = n & 31;
    gzoT[tid] = f2bf(W[((nb*HH + h)*32 + k)*32 + nn]); return;
  }
}

// ---------------- LN1 + causal depthwise conv + silu ----------------
// useemb: read rows from emb[tok] (nb=0) and also materialize x; else read x.
__global__ __launch_bounds__(256) void k_lnconv(float* __restrict__ x,
    const int* __restrict__ tok, const float* __restrict__ emb,
    const float* __restrict__ ln1_w, const float* __restrict__ conv_w,
    const float* __restrict__ conv_b, u16* __restrict__ xn_bf,
    u16* __restrict__ xc_bf, int nb, int useemb){
  __shared__ float lnbuf[35][128];
  int b = blockIdx.x >> 2, tile = blockIdx.x & 3;
  int t0 = tile * 32;
  int wid = threadIdx.x >> 6, l = threadIdx.x & 63;
  for (int tt = wid; tt < 35; tt += 4){
    int t = t0 - 3 + tt;
    if (t < 0){
      lnbuf[tt][2*l] = 0.f; lnbuf[tt][2*l+1] = 0.f;
    } else {
      const float* src = useemb ? (emb + (size_t)tok[b*TT + t]*128)
                                : (x + (size_t)(b*TT + t)*128);
      float2 v = ((const float2*)src)[l];
      float s  = wsum64(v.x + v.y);
      float sq = wsum64(v.x*v.x + v.y*v.y);
      float mu = s * (1.f/128.f);
      float var = sq * (1.f/128.f) - mu*mu;
      float rs = rsqrtf(var + EPSF);
      float2 w = ((const float2*)(ln1_w + nb*128))[l];
      float y0 = (v.x - mu)*rs*w.x, y1 = (v.y - mu)*rs*w.y;
      lnbuf[tt][2*l] = y0; lnbuf[tt][2*l+1] = y1;
      if (tt >= 3){
        u32 pk = (u32)f2bf(y0) | ((u32)f2bf(y1) << 16);
        ((u32*)(xn_bf + (size_t)(b*TT + t)*128))[l] = pk;
        if (useemb) ((float2*)(x + (size_t)(b*TT + t)*128))[l] = v;
      }
    }
  }
  __syncthreads();
  for (int e = threadIdx.x; e < 32*128; e += 256){
    int tt = e >> 7, d = e & 127;
    float s = conv_b[nb*128 + d];
    #pragma unroll
    for (int k = 0; k < 4; k++)
      s += lnbuf[tt + k][d] * conv_w[(nb*128 + d)*4 + k];
    float sig = 1.f / (1.f + __expf(-s));
    xc_bf[(size_t)(b*TT + t0 + tt)*128 + d] = f2bf(s * sig);
  }
}

// ------ sLSTM scan with FUSED gate projection (k_gates eliminated) ----------
// one wave per (batch, head). Per 32-t chunk: 16 MFMAs project gates into
// wave-private LDS [col(128)][36] (bit-identical f2bf path to old k_gates),
// A-frags prefetched one chunk ahead; then 32 scan steps (R15 body) read
// gates from LDS. No __syncthreads (waves independent). x 4-deep prefetch.
__global__ __launch_bounds__(256, 2) void k_scan(const u16* __restrict__ xc_bf,
    const u16* __restrict__ xn_bf, const u16* __restrict__ gifT,
    const u16* __restrict__ gzoT, const float* __restrict__ Rk,
    const float* __restrict__ cell_b, const float* __restrict__ gn_w,
    float* __restrict__ x, float* __restrict__ dump, int nb){
  __shared__ u16 glds[4][128][36];
  int wid = threadIdx.x >> 6, l = threadIdx.x & 63;
  int pair = blockIdx.x * 4 + wid;       // 2048 chains
  int b = pair >> 2, h = pair & 3;
  u16 (*gw)[36] = glds[wid];
  f32x2 rk[32];
  const float* Rkh = Rk + (size_t)(nb*HH + h)*32*128;
  #pragma unroll
  for (int d = 0; d < 32; d++){
    rk[d].x = Rkh[d*128 + l];
    rk[d].y = Rkh[d*128 + l + 64];
  }
  short8 bfr[2][4];
  {
    const u16* B0 = gifT + (size_t)(nb*HH + h)*64*32;
    const u16* B1 = gzoT + (size_t)(nb*HH + h)*64*32;
    #pragma unroll
    for (int jt = 0; jt < 4; jt++){
      bfr[0][jt] = *(const short8*)(B0 + (jt*16 + (l & 15))*32 + (l >> 4)*8);
      bfr[1][jt] = *(const short8*)(B1 + (jt*16 + (l & 15))*32 + (l >> 4)*8);
    }
  }
  f32x2 cb = { cell_b[(nb*HH + h)*128 + l], cell_b[(nb*HH + h)*128 + l + 64] };
  int e = l & 31;
  bool lo = (l < 32);
  float gnw = gn_w[nb*128 + h*32 + e];
  float hs = 0.f, cs = 0.f, ns = 0.f, ms = 0.f;
  // A-frag bases (row = (l&15) + t, col = h*32 + (l>>4)*8) — as old k_gates
  const u16* baseA0 = xc_bf + ((size_t)(b*TT) + (l & 15))*128 + h*32 + (l >> 4)*8;
  const u16* baseA1 = xn_bf + ((size_t)(b*TT) + (l & 15))*128 + h*32 + (l >> 4)*8;
  short8 afr[2][2];
  #pragma unroll
  for (int rg = 0; rg < 2; rg++){
    afr[0][rg] = *(const short8*)(baseA0 + (size_t)(rg*16)*128);
    afr[1][rg] = *(const short8*)(baseA1 + (size_t)(rg*16)*128);
  }
  // always-exec residual pointers: hi lanes use a per-wave dump row (stride 0)
  float* xp = lo ? (x + (size_t)(b*TT)*128 + h*32 + e) : (dump + pair*32 + e);
  int xstr = lo ? 128 : 0;
  float xq0 = xp[0];
  float xq1 = xp[xstr];
  float xq2 = xp[2*xstr];
  float xq3 = xp[3*xstr];
  for (int ct = 0; ct < 4; ct++){
    // --- gate-projection MFMA phase into wave-private LDS
    #pragma unroll
    for (int z = 0; z < 2; z++){
      #pragma unroll
      for (int rg = 0; rg < 2; rg++){
        short8 a = afr[z][rg];
        int tloc = rg*16 + (l >> 4)*4;
        #pragma unroll
        for (int jt = 0; jt < 4; jt++){
          f32x4 acc = {0.f, 0.f, 0.f, 0.f};
          acc = __builtin_amdgcn_mfma_f32_16x16x32_bf16(a, bfr[z][jt], acc, 0, 0, 0);
          int cloc = z*64 + jt*16 + (l & 15);
          s16x4 pk;
          #pragma unroll
          for (int r = 0; r < 4; r++) pk[r] = (short)f2bf(acc[r]);
          *(s16x4*)(&gw[cloc][tloc]) = pk;
        }
      }
    }
    // prefetch next chunk's A-frags (completes under the 32 scan steps)
    if (ct < 3){
      #pragma unroll
      for (int rg = 0; rg < 2; rg++){
        afr[0][rg] = *(const short8*)(baseA0 + (size_t)((ct+1)*32 + rg*16)*128);
        afr[1][rg] = *(const short8*)(baseA1 + (size_t)((ct+1)*32 + rg*16)*128);
      }
    }
    // --- 32 scan steps from LDS
    for (int t8g = 0; t8g < 4; t8g++){
      s16x4 galo = *(const s16x4*)(&gw[l][t8g*8]);
      s16x4 gahi = *(const s16x4*)(&gw[l][t8g*8 + 4]);
      s16x4 gblo = *(const s16x4*)(&gw[l + 64][t8g*8]);
      s16x4 gbhi = *(const s16x4*)(&gw[l + 64][t8g*8 + 4]);
      #pragma unroll
      for (int k = 0; k < 8; k++){
        u16 g0 = (u16)(k < 4 ? galo[k & 3] : gahi[k & 3]);
        u16 g1 = (u16)(k < 4 ? gblo[k & 3] : gbhi[k & 3]);
        float xcur = xq0;
        xq0 = xq1; xq1 = xq2; xq2 = xq3;
        xq3 = xp[4*xstr];                  // load for step t+4 (overread ws-safe)
        f32x2 acc0 = { bf2f(g0) + cb.x, bf2f(g1) + cb.y };
        f32x2 acc1 = {0.f, 0.f}, acc2 = {0.f, 0.f}, acc3 = {0.f, 0.f};
        #pragma unroll
        for (int d = 0; d < 32; d += 4){
          float h0 = bcastf(hs, d),   h1 = bcastf(hs, d+1);
          float h2 = bcastf(hs, d+2), h3 = bcastf(hs, d+3);
          acc0 = __builtin_elementwise_fma((f32x2){h0,h0}, rk[d],   acc0);
          acc1 = __builtin_elementwise_fma((f32x2){h1,h1}, rk[d+1], acc1);
          acc2 = __builtin_elementwise_fma((f32x2){h2,h2}, rk[d+2], acc2);
          acc3 = __builtin_elementwise_fma((f32x2){h3,h3}, rk[d+3], acc3);
        }
        f32x2 rr = (acc0 + acc1) + (acc2 + acc3);
        float r0 = rr.x, r1 = rr.y;          // lanes<32: ir, zr ; lanes>=32: fr, og
        float fx = down32(r0);               // lanes<32 get fr[e]
        float ox = down32(r1);               // lanes<32 get og[e]
        float mnew = fmaxf(fx + ms, r0);
        float ig = __builtin_amdgcn_exp2f((r0 - mnew) * LOG2E);
        float fg = __builtin_amdgcn_exp2f((fx + ms - mnew) * LOG2E);
        float e2 = __builtin_amdgcn_exp2f(2.f * LOG2E * r1);
        float th = fmaf(-2.f, __builtin_amdgcn_rcpf(e2 + 1.f), 1.f);   // tanh(zr)
        cs = fmaf(fg, cs, ig * th);
        ns = fmaf(fg, ns, ig);
        ms = mnew;
        float se = __builtin_amdgcn_exp2f(-ox * LOG2E);
        hs = cs * __builtin_amdgcn_rcpf(fmaf(ns, se, ns));
        // group norm over lanes 0..31 via DPP (no cross-wave LDS)
        float s = rsum_rows01(hs);
        float sq = rsum_rows01(hs * hs);
        float mu = bcastf(s, 31) * (1.f/32.f);
        float var = bcastf(sq, 31) * (1.f/32.f) - mu*mu;
        float yn = (hs - mu) * __builtin_amdgcn_rsqf(var + EPSF) * gnw;
        xp[0] = xcur + yn;
        xp += xstr;
      }
    }
  }
}

// ---------------- fused LN2 + FFN (N-partitioned, W loaded once/block) -------
__global__ __launch_bounds__(512, 4) void k_ffn(float* __restrict__ x,
    const float* __restrict__ ln2_w, const u16* __restrict__ w1T,
    const float* __restrict__ ff_b1, const u16* __restrict__ w2T,
    const float* __restrict__ ff_b2, int nb){
  __shared__ u16 xln[64][136];
  __shared__ u16 hbuf[64][392];
  int m0 = blockIdx.x * 64;
  int w = threadIdx.x >> 6, l = threadIdx.x & 63;
  short8 w1f[3][4];
  const u16* W1 = w1T + (size_t)nb*384*128;
  #pragma unroll
  for (int j = 0; j < 3; j++)
    #pragma unroll
    for (int c = 0; c < 4; c++)
      w1f[j][c] = *(const short8*)(W1 + (size_t)((3*w + j)*16 + (l & 15))*128 + c*32 + (l >> 4)*8);
  short8 w2f[6];
  const u16* W2 = w2T + (size_t)nb*128*192;
  #pragma unroll
  for (int c = 0; c < 6; c++)
    w2f[c] = *(const short8*)(W2 + (size_t)(w*16 + (l & 15))*192 + c*32 + (l >> 4)*8);
  float2 lw = ((const float2*)(ln2_w + nb*128))[l];
  #pragma unroll
  for (int rr = 0; rr < 8; rr++){
    int row = w*8 + rr;
    float2 v = ((const float2*)(x + (size_t)(m0 + row)*128))[l];
    float s  = wsum64(v.x + v.y);
    float sq = wsum64(v.x*v.x + v.y*v.y);
    float mu = s * (1.f/128.f);
    float var = sq * (1.f/128.f) - mu*mu;
    float rs = rsqrtf(var + EPSF);
    ((u32*)xln[row])[l] = (u32)f2bf((v.x - mu)*rs*lw.x)
                        | ((u32)f2bf((v.y - mu)*rs*lw.y) << 16);
  }
  __syncthreads();
  #pragma unroll
  for (int rg = 0; rg < 4; rg++){
    short8 a[4];
    #pragma unroll
    for (int c = 0; c < 4; c++)
      a[c] = *(const short8*)(&xln[rg*16 + (l & 15)][c*32 + (l >> 4)*8]);
    #pragma unroll
    for (int j = 0; j < 3; j++){
      f32x4 acc = {0.f, 0.f, 0.f, 0.f};
      #pragma unroll
      for (int c = 0; c < 4; c++)
        acc = __builtin_amdgcn_mfma_f32_16x16x32_bf16(a[c], w1f[j][c], acc, 0, 0, 0);
      int col = (3*w + j)*16 + (l & 15);
      float bb = ff_b1[nb*384 + col];
      #pragma unroll
      for (int r = 0; r < 4; r++){
        int row = rg*16 + (l >> 4)*4 + r;
        hbuf[row][col] = f2bf(acc[r] + bb);
      }
    }
  }
  __syncthreads();
  {
    int row = threadIdx.x >> 3;
    int k0 = (threadIdx.x & 7) * 24;
    #pragma unroll
    for (int j2 = 0; j2 < 24; j2++){
      int k = k0 + j2;
      float gt = bf2f(hbuf[row][k]);
      float u = bf2f(hbuf[row][k + 192]);
      hbuf[row][k] = f2bf(gelu_fast(gt) * u);
    }
  }
  __syncthreads();
  #pragma unroll
  for (int rg = 0; rg < 4; rg++){
    f32x4 acc = {0.f, 0.f, 0.f, 0.f};
    #pragma unroll
    for (int c = 0; c < 6; c++){
      short8 a = *(const short8*)(&hbuf[rg*16 + (l & 15)][c*32 + (l >> 4)*8]);
      acc = __builtin_amdgcn_mfma_f32_16x16x32_bf16(a, w2f[c], acc, 0, 0, 0);
    }
    int col = w*16 + (l & 15);
    float bb = ff_b2[nb*128 + col];
    #pragma unroll
    for (int r = 0; r < 4; r++){
      int row = m0 + rg*16 + (l >> 4)*4 + r;
      x[(size_t)row*128 + col] += acc[r] + bb;
    }
  }
}

// ---------------- post-LN + mean-pool + classifier ----------------
__global__ __launch_bounds__(256) void k_pool_cls(const float* __restrict__ x,
    const float* __restrict__ pw, const float* __restrict__ w1,
    const float* __restrict__ b1, const float* __restrict__ w2,
    const float* __restrict__ b2, float* __restrict__ out){
  __shared__ float red[4][128];
  __shared__ float pooled[128];
  __shared__ float h1s[64];
  int b = blockIdx.x;
  int wid = threadIdx.x >> 6, l = threadIdx.x & 63;
  float2 w = ((const float2*)pw)[l];
  float ax = 0.f, ay = 0.f;
  for (int t = wid; t < TT; t += 4){
    float2 v = ((const float2*)(x + (size_t)(b*TT + t)*128))[l];
    float s  = wsum64(v.x + v.y);
    float sq = wsum64(v.x*v.x + v.y*v.y);
    float mu = s * (1.f/128.f);
    float var = sq * (1.f/128.f) - mu*mu;
    float rs = rsqrtf(var + EPSF);
    ax += (v.x - mu)*rs*w.x;
    ay += (v.y - mu)*rs*w.y;
  }
  red[wid][2*l] = ax; red[wid][2*l+1] = ay;
  __syncthreads();
  if (threadIdx.x < 128){
    int d = threadIdx.x;
    pooled[d] = (red[0][d] + red[1][d] + red[2][d] + red[3][d]) * (1.f/128.f);
  }
  __syncthreads();
  if (threadIdx.x < 64){
    int j = threadIdx.x;
    float s = b1[j];
    for (int d = 0; d < 128; d++) s += pooled[d] * w1[d*64 + j];
    h1s[j] = fmaxf(s, 0.f);
  }
  __syncthreads();
  if (threadIdx.x < 2){
    int j = threadIdx.x;
    float s = b2[j];
    for (int k = 0; k < 64; k++) s += h1s[k] * w2[k*2 + j];
    out[b*2 + j] = s;
  }
}

extern "C" void kernel_launch(void* const* d_in, const int* in_sizes, int n_in,
                              void* d_out, int out_size, void* d_ws, size_t ws_size,
                              hipStream_t stream){
  const int*   tok    = (const int*)d_in[0];
  const float* emb    = (const float*)d_in[1];
  const float* ln1_w  = (const float*)d_in[2];
  const float* conv_w = (const float*)d_in[3];
  const float* conv_b = (const float*)d_in[4];
  const float* Wi     = (const float*)d_in[5];
  const float* Wf     = (const float*)d_in[6];
  const float* Wz     = (const float*)d_in[7];
  const float* Wo     = (const float*)d_in[8];
  const float* Rk     = (const float*)d_in[9];
  const float* cell_b = (const float*)d_in[10];
  const float* gn_w   = (const float*)d_in[11];
  const float* ln2_w  = (const float*)d_in[12];
  const float* ff_w1  = (const float*)d_in[13];
  const float* ff_b1  = (const float*)d_in[14];
  const float* ff_w2  = (const float*)d_in[15];
  const float* ff_b2  = (const float*)d_in[16];
  const float* postw  = (const float*)d_in[17];
  const float* cw1    = (const float*)d_in[18];
  const float* cb1    = (const float*)d_in[19];
  const float* cw2    = (const float*)d_in[20];
  const float* cb2    = (const float*)d_in[21];
  float* out = (float*)d_out;

  char* ws = (char*)d_ws;
  size_t off = 0;
  float* x      = (float*)(ws + off); off += (size_t)BT*128*4;
  float* dump   = (float*)(ws + off); off += (size_t)2048*32*4;   // own region (xn/xc now live during scan)
  u16*   xn_bf  = (u16*)(ws + off);   off += (size_t)BT*128*2;
  u16*   xc_bf  = (u16*)(ws + off);   off += (size_t)BT*128*2;
  u16*   w1T    = (u16*)(ws + off);   off += (size_t)NBB*384*128*2;
  u16*   w2T    = (u16*)(ws + off);   off += (size_t)NBB*128*192*2;
  u16*   gifT   = (u16*)(ws + off);   off += (size_t)NBB*HH*64*32*2;
  u16*   gzoT   = (u16*)(ws + off);   off += (size_t)NBB*HH*64*32*2;

  k_convert<<<704, 256, 0, stream>>>(ff_w1, ff_w2, Wi, Wf, Wz, Wo, w1T, w2T, gifT, gzoT);
  for (int nb = 0; nb < NBB; nb++){
    k_lnconv<<<BB*4, 256, 0, stream>>>(x, tok, emb, ln1_w, conv_w, conv_b,
                                       xn_bf, xc_bf, nb, nb == 0 ? 1 : 0);
    k_scan<<<512, 256, 0, stream>>>(xc_bf, xn_bf, gifT, gzoT, Rk, cell_b,
                                    gn_w, x, dump, nb);
    k_ffn<<<BT/64, 512, 0, stream>>>(x, ln2_w, w1T, ff_b1, w2T, ff_b2, nb);
  }
  k_pool_cls<<<BB, 256, 0, stream>>>(x, postw, cw1, cb1, cw2, cb2, out);
}